// Round 12
// baseline (1021.260 us; speedup 1.0000x reference)
//
#include <hip/hip_runtime.h>
#include <hip/hip_bf16.h>
#include <math.h>

#define NB 16384
#define ND 256
#define NH 2048
#define NOUT 255

constexpr float C_ALPHA  = 0.01f;
constexpr float C_REHU_D = 0.01f;
constexpr float C_PSD_D  = 1.0f;
constexpr float C_EPS    = 1e-5f;

typedef unsigned short u16;
typedef short bf16x8 __attribute__((ext_vector_type(8)));
typedef float f32x4 __attribute__((ext_vector_type(4)));

#define GAS __attribute__((address_space(1)))
#define LAS __attribute__((address_space(3)))

// ---- scratch in device globals ----
__device__ u16   g_xbf [(size_t)NB * ND];
__device__ u16   g_buf1[(size_t)NB * NH];   // h1 -> g_a2
__device__ u16   g_buf2[(size_t)NB * NH];   // h2 -> g_a1
__device__ u16   g_z1  [(size_t)NB * NH];   // rehu(a1) bf16
__device__ u16   g_a2b [(size_t)NB * NH];   // a2 bf16
__device__ float g_fxb [(size_t)NB * ND];
__device__ float g_gVb [(size_t)NB * ND];
__device__ u16   g_fW0b[(size_t)NH * ND];
__device__ u16   g_fW1b[(size_t)NH * NH];
__device__ u16   g_fW2b[(size_t)ND * NH];   // padded: row 255 = 0
__device__ u16   g_vW0b[(size_t)NH * ND];
__device__ u16   g_vW1b[(size_t)NH * ND];
__device__ u16   g_spU0b [(size_t)NH * NH];  // softplus(vU0)/NH
__device__ u16   g_spU0Tb[(size_t)NH * NH];  // transpose of above
__device__ u16   g_vW0Tb[(size_t)ND * NH];
__device__ u16   g_vW1Tb[(size_t)ND * NH];
__device__ float g_fb2p[ND];
__device__ float g_spU1[NH];
__device__ float g_z10[NH];
__device__ float g_a20[NH];
__device__ float g_ic0[1];
__device__ float g_zacc[NB];
__device__ float g_sS [NB];
__device__ float g_sVx[NB];

__device__ __forceinline__ float softplus_f(float x) {
    return fmaxf(x, 0.0f) + log1pf(expf(-fabsf(x)));
}
__device__ __forceinline__ float rehu_f(float x, float d) {
    float t = x * fabsf(x) / (2.0f * d);
    t = fminf(fmaxf(t, 0.0f), 0.5f * d);
    return fmaxf(t, x - 0.5f * d);
}
__device__ __forceinline__ float drehu_f(float x, float d) {
    return fminf(fmaxf(x / d, 0.0f), 1.0f);
}
__device__ __forceinline__ u16 f2b(float v) {
    __hip_bfloat16 b = __float2bfloat16(v);
    return *reinterpret_cast<u16*>(&b);
}
__device__ __forceinline__ float b2f(u16 v) {
    unsigned u = ((unsigned)v) << 16;
    return __uint_as_float(u);
}

// valid result on thread 0 only
__device__ __forceinline__ float block_reduce_sum(float v, float* sbuf) {
    #pragma unroll
    for (int off = 32; off > 0; off >>= 1) v += __shfl_down(v, off, 64);
    const int lane = threadIdx.x & 63;
    const int wid  = threadIdx.x >> 6;
    if (lane == 0) sbuf[wid] = v;
    __syncthreads();
    float r = 0.0f;
    if (wid == 0) {
        r = (lane < 4) ? sbuf[lane] : 0.0f;
        r += __shfl_down(r, 2, 64);
        r += __shfl_down(r, 1, 64);
    }
    __syncthreads();
    return r;
}

// ======================= 256^2 8-phase bf16 MFMA GEMM =======================
// Y = A @ B^T (+bias), A [M x K] bf16, B [N x K] bf16 (two K-segments),
// 512 thr / 8 waves (2Mx4N), BK=64, 128KiB LDS dbuf, 3-bit XOR swizzle.
// Deep pipeline: stages for tile t+2 issued in phases C/D of tile t (right
// after the target LDS regions' last readers barrier out); single counted
// vmcnt(8) per K-tile (tile t+1's loads were issued 4-5 phases earlier);
// drain vmcnt(0) on the final quads where stages are skipped. No explicit
// lgkmcnt: reads are compiler-visible, hipcc emits counted waits (m97/G7).
// EPI 0: Ybf=bf16(relu(v+bias))
// EPI 2: Ybf=bf16(rehu(v+bias,0.01))
// EPI 3: Ybf=bf16(v+bias); zacc[row]+=sum_col rehu(v+bias)*spU1[col]
// EPI 4: Ybf=bf16(v*min(1,sqrt(200*aux)))
template<int EPI>
__global__ __launch_bounds__(512, 2) void gemm8(
    u16* __restrict__ Ybf,
    const u16* __restrict__ A0, int lda0, const u16* __restrict__ B0, int ldb0, int nt0,
    const u16* __restrict__ A1, int lda1, const u16* __restrict__ B1, int ldb1,
    const float* __restrict__ bias, const u16* __restrict__ auxb,
    float* __restrict__ zacc, const float* __restrict__ spU1,
    int N, int nt)
{
    __shared__ u16 smem[65536];           // 128 KiB
    char* lb = (char*)smem;

    const int nwg = gridDim.x;
    const int bid = blockIdx.x;
    const int swz = (bid & 7) * (nwg >> 3) + (bid >> 3);  // XCD swizzle (nwg%8==0)
    const int ntn = N >> 8;
    const int tm = swz / ntn, tn = swz % ntn;
    const int row0 = tm * 256, col0 = tn * 256;

    const int tid  = threadIdx.x;
    const int lane = tid & 63;
    const int wv   = tid >> 6;
    const int wr = wv >> 2, wc = wv & 3;
    const int l15 = lane & 15;
    const int lhi = lane >> 4;

    f32x4 acc[8][4] = {};
    bf16x8 aM[4][2], bLo[2][2], bHi[2][2];

    // stage one half-tile (128x64 bf16) of K-tile kt. h:0=A-lo,1=A-hi,2=B-lo,3=B-hi
    auto stage = [&](int kt, int h) {
        if (kt >= nt) return;
        const u16* base; int ld, k0;
        if (kt < nt0) { base = (h < 2) ? A0 : B0; ld = (h < 2) ? lda0 : ldb0; k0 = kt * 64; }
        else          { base = (h < 2) ? A1 : B1; ld = (h < 2) ? lda1 : ldb1; k0 = (kt - nt0) * 64; }
        const int r0 = ((h < 2) ? row0 : col0) + (h & 1) * 128;
        char* dst = lb + (kt & 1) * 65536 + (h >> 1) * 32768 + (h & 1) * 16384;
        #pragma unroll
        for (int s = 0; s < 2; ++s) {
            const int o  = s * 8192 + wv * 1024 + lane * 16;      // linear dest offset
            const int op = o ^ (((o >> 7) & 7) << 4);             // 3-bit pre-swizzled source
            const u16* src = base + (size_t)(r0 + (op >> 7)) * ld + k0 + ((op & 127) >> 1);
            __builtin_amdgcn_global_load_lds((const GAS void*)src,
                                             (LAS void*)(dst + s * 8192 + wv * 1024), 16, 0, 0);
        }
    };
    // swizzled LDS fragment read: region byte offset + logical (row, colbyte)
    auto lrd = [&](int off, int lrow, int cb) -> bf16x8 {
        int o = lrow * 128 + cb;
        o ^= ((o >> 7) & 7) << 4;
        return *reinterpret_cast<const bf16x8*>(lb + off + o);
    };

    // 4 phases computing the K-tile living in buffer bufo; stages K-tile kn
    // (= current tile + 2, same buffer parity) into the regions as they free.
    auto quad = [&](int bufo, int kn) {
        const int aoff = bufo + wr * 16384;
        const int boff = bufo + 32768 + (wc >> 1) * 16384;
        const int brow = (wc & 1) * 64;
        // ---- phase A: read A m0-3 + B n0-1 (12 reads); MFMA m0-3 x n0-1 ----
        #pragma unroll
        for (int m = 0; m < 4; ++m)
            #pragma unroll
            for (int ks = 0; ks < 2; ++ks)
                aM[m][ks] = lrd(aoff, m * 16 + l15, ks * 64 + lhi * 16);
        #pragma unroll
        for (int n = 0; n < 2; ++n)
            #pragma unroll
            for (int ks = 0; ks < 2; ++ks)
                bLo[n][ks] = lrd(boff, brow + n * 16 + l15, ks * 64 + lhi * 16);
        __builtin_amdgcn_s_barrier();
        __builtin_amdgcn_s_setprio(1);
        #pragma unroll
        for (int m = 0; m < 4; ++m)
            #pragma unroll
            for (int n = 0; n < 2; ++n)
                #pragma unroll
                for (int ks = 0; ks < 2; ++ks)
                    acc[m][n] = __builtin_amdgcn_mfma_f32_16x16x32_bf16(aM[m][ks], bLo[n][ks], acc[m][n], 0, 0, 0);
        __builtin_amdgcn_s_setprio(0);
        __builtin_amdgcn_s_barrier();
        // ---- phase B: read B n2-3 (4 reads); MFMA m0-3 x n2-3 ----
        #pragma unroll
        for (int n = 0; n < 2; ++n)
            #pragma unroll
            for (int ks = 0; ks < 2; ++ks)
                bHi[n][ks] = lrd(boff, brow + (2 + n) * 16 + l15, ks * 64 + lhi * 16);
        __builtin_amdgcn_s_barrier();
        __builtin_amdgcn_s_setprio(1);
        #pragma unroll
        for (int m = 0; m < 4; ++m)
            #pragma unroll
            for (int n = 0; n < 2; ++n)
                #pragma unroll
                for (int ks = 0; ks < 2; ++ks)
                    acc[m][2 + n] = __builtin_amdgcn_mfma_f32_16x16x32_bf16(aM[m][ks], bHi[n][ks], acc[m][2 + n], 0, 0, 0);
        __builtin_amdgcn_s_setprio(0);
        __builtin_amdgcn_s_barrier();
        // ---- phase C: read A m4-7 (8 reads); stage kn B-halves (regions freed
        //      by the end-of-phase-B barrier); MFMA m4-7 x n2-3 ----
        #pragma unroll
        for (int m = 0; m < 4; ++m)
            #pragma unroll
            for (int ks = 0; ks < 2; ++ks)
                aM[m][ks] = lrd(aoff, (4 + m) * 16 + l15, ks * 64 + lhi * 16);
        stage(kn, 2);
        stage(kn, 3);
        __builtin_amdgcn_s_barrier();
        __builtin_amdgcn_s_setprio(1);
        #pragma unroll
        for (int m = 0; m < 4; ++m)
            #pragma unroll
            for (int n = 0; n < 2; ++n)
                #pragma unroll
                for (int ks = 0; ks < 2; ++ks)
                    acc[4 + m][2 + n] = __builtin_amdgcn_mfma_f32_16x16x32_bf16(aM[m][ks], bHi[n][ks], acc[4 + m][2 + n], 0, 0, 0);
        __builtin_amdgcn_s_setprio(0);
        __builtin_amdgcn_s_barrier();
        // ---- phase D: stage kn A-halves (freed by end-of-phase-C barrier);
        //      MFMA m4-7 x n0-1; counted vmcnt(8) (tile t+1 staged 4-5 phases
        //      ago is forced complete; kn's 8 loads may stay in flight) ----
        stage(kn, 0);
        stage(kn, 1);
        __builtin_amdgcn_s_barrier();
        __builtin_amdgcn_s_setprio(1);
        #pragma unroll
        for (int m = 0; m < 4; ++m)
            #pragma unroll
            for (int n = 0; n < 2; ++n)
                #pragma unroll
                for (int ks = 0; ks < 2; ++ks)
                    acc[4 + m][n] = __builtin_amdgcn_mfma_f32_16x16x32_bf16(aM[m][ks], bLo[n][ks], acc[4 + m][n], 0, 0, 0);
        __builtin_amdgcn_s_setprio(0);
        if (kn >= nt) asm volatile("s_waitcnt vmcnt(0)" ::: "memory");
        else          asm volatile("s_waitcnt vmcnt(8)" ::: "memory");
        __builtin_amdgcn_s_barrier();
    };

    // ---- prologue: stage K-tiles 0 and 1 fully (16 loads); wait tile 0 ----
    #pragma unroll
    for (int h = 0; h < 4; ++h) stage(0, h);
    #pragma unroll
    for (int h = 0; h < 4; ++h) stage(1, h);
    asm volatile("s_waitcnt vmcnt(8)" ::: "memory");
    __builtin_amdgcn_s_barrier();

    const int nit = nt >> 1;
    for (int i = 0; i < nit; ++i) {
        quad(0,     2 * i + 2);   // phases 1-4: compute K-tile 2i   (buf0), stage 2i+2
        quad(65536, 2 * i + 3);   // phases 5-8: compute K-tile 2i+1 (buf1), stage 2i+3
    }

    // ---- epilogue ----
    #pragma unroll
    for (int m = 0; m < 8; ++m) {
        float rp[4] = {0.f, 0.f, 0.f, 0.f};
        #pragma unroll
        for (int n = 0; n < 4; ++n) {
            const int col = col0 + wc * 64 + n * 16 + l15;
            float bv = 0.0f, spv = 0.0f;
            if (EPI == 0 || EPI == 2 || EPI == 3) bv = bias[col];
            if (EPI == 3) spv = spU1[col];
            #pragma unroll
            for (int q = 0; q < 4; ++q) {
                const int row = row0 + wr * 128 + m * 16 + (lhi << 2) + q;
                const size_t idx = (size_t)row * N + col;
                float v = acc[m][n][q] + bv;
                if (EPI == 0) {
                    Ybf[idx] = f2b(fmaxf(v, 0.0f));
                } else if (EPI == 2) {
                    Ybf[idx] = f2b(rehu_f(v, C_REHU_D));
                } else if (EPI == 3) {
                    Ybf[idx] = f2b(v);
                    rp[q] += rehu_f(v, C_REHU_D) * spv;
                } else { // EPI 4
                    const float z = b2f(auxb[idx]);
                    Ybf[idx] = f2b(v * fminf(sqrtf(200.0f * z), 1.0f));
                }
            }
        }
        if (EPI == 3) {
            #pragma unroll
            for (int q = 0; q < 4; ++q) {
                float s = rp[q];
                s += __shfl_xor(s, 1, 64);
                s += __shfl_xor(s, 2, 64);
                s += __shfl_xor(s, 4, 64);
                s += __shfl_xor(s, 8, 64);
                if (l15 == 0) atomicAdd(&zacc[row0 + wr * 128 + m * 16 + (lhi << 2) + q], s);
            }
        }
    }
}

// ======================= 128^2 MFMA GEMM (atomic fp32 output) =======================
// SEG==0: split-K, koff = blockIdx.y*K, operands (A,B)
// SEG==1: blockIdx.y selects segment: 0 -> (A,B), 1 -> (A2,B2); full K each
#define BM 128
#define BN 128
#define BK 32

template<int SEG>
__global__ __launch_bounds__(256) void mfma_gemm(
    float* __restrict__ Y32,
    const u16* __restrict__ A, const u16* __restrict__ Bm, int lda, int ldb,
    const u16* __restrict__ A2, const u16* __restrict__ B2,
    int M, int N, int K)
{
    __shared__ u16 As[BM * BK];
    __shared__ u16 Bs[BN * BK];

    const int ntn = N >> 7;
    const int nwg = gridDim.x;
    const int bid = blockIdx.x;
    const int swz = (bid & 7) * (nwg >> 3) + (bid >> 3);
    const int tm = swz / ntn, tn = swz % ntn;
    const int row0 = tm * BM, col0 = tn * BN;

    const u16* Abase = (SEG && blockIdx.y) ? A2 : A;
    const u16* Bbase = (SEG && blockIdx.y) ? B2 : Bm;
    const int koff = SEG ? 0 : blockIdx.y * K;

    const int tid  = threadIdx.x;
    const int lane = tid & 63;
    const int wave = tid >> 6;
    const int wr = wave >> 1, wc = wave & 1;

    f32x4 acc[4][4] = {};

    char* AsB = (char*)As + wave * 1024;
    char* BsB = (char*)Bs + wave * 1024;
    const int lr = lane & 15;
    const int lk = (lane >> 4) << 3;

    const u16* Ag = Abase + (size_t)(row0 + (tid >> 2)) * lda + ((tid & 3) << 3) + koff;
    const u16* Bg = Bbase + (size_t)(col0 + (tid >> 2)) * ldb + ((tid & 3) << 3) + koff;

    for (int k0 = 0; k0 < K; k0 += BK) {
        __builtin_amdgcn_global_load_lds((const GAS void*)(Ag + k0), (LAS void*)(AsB), 16, 0, 0);
        __builtin_amdgcn_global_load_lds((const GAS void*)(Ag + (size_t)64 * lda + k0), (LAS void*)(AsB + 4096), 16, 0, 0);
        __builtin_amdgcn_global_load_lds((const GAS void*)(Bg + k0), (LAS void*)(BsB), 16, 0, 0);
        __builtin_amdgcn_global_load_lds((const GAS void*)(Bg + (size_t)64 * ldb + k0), (LAS void*)(BsB + 4096), 16, 0, 0);
        __syncthreads();

        bf16x8 af[4], bfr[4];
        #pragma unroll
        for (int m = 0; m < 4; ++m)
            af[m] = *reinterpret_cast<const bf16x8*>(&As[(wr * 64 + m * 16 + lr) * BK + lk]);
        #pragma unroll
        for (int n = 0; n < 4; ++n)
            bfr[n] = *reinterpret_cast<const bf16x8*>(&Bs[(wc * 64 + n * 16 + lr) * BK + lk]);
        #pragma unroll
        for (int m = 0; m < 4; ++m)
            #pragma unroll
            for (int n = 0; n < 4; ++n)
                acc[m][n] = __builtin_amdgcn_mfma_f32_16x16x32_bf16(af[m], bfr[n], acc[m][n], 0, 0, 0);
        __syncthreads();
    }

    const int rr = (lane >> 4) << 2;
    #pragma unroll
    for (int m = 0; m < 4; ++m) {
        #pragma unroll
        for (int n = 0; n < 4; ++n) {
            const int col = col0 + wc * 64 + n * 16 + lr;
            #pragma unroll
            for (int i = 0; i < 4; ++i) {
                const int row = row0 + wr * 64 + m * 16 + rr + i;
                atomicAdd(&Y32[(size_t)row * N + col], acc[m][n][i]);
            }
        }
    }
}

// ======================= small helper kernels =======================
template<int OP>  // 0 identity, 2 softplus/NH
__global__ void cast_kernel(u16* __restrict__ dst, const float* __restrict__ src, long n) {
    long i = (long)blockIdx.x * blockDim.x + threadIdx.x;
    const long stride = (long)gridDim.x * blockDim.x;
    for (; i < n; i += stride) {
        float v = src[i];
        if (OP == 2) v = softplus_f(v) * (1.0f / NH);
        dst[i] = f2b(v);
    }
}

__global__ void castpad_kernel(u16* __restrict__ dst, const float* __restrict__ src,
                               long nsrc, long ntot) {
    long i = (long)blockIdx.x * blockDim.x + threadIdx.x;
    const long stride = (long)gridDim.x * blockDim.x;
    for (; i < ntot; i += stride) dst[i] = (i < nsrc) ? f2b(src[i]) : (u16)0;
}

template<int OP>  // dst[c*R + r] = op(src[r*C + c]); grid (C/32, R/32), block (32,8)
__global__ __launch_bounds__(256) void transpose_cast_kernel(
    u16* __restrict__ dst, const float* __restrict__ src, int R, int C)
{
    __shared__ float t[32][33];
    const int c0 = blockIdx.x * 32, r0 = blockIdx.y * 32;
    for (int i = threadIdx.y; i < 32; i += 8)
        t[i][threadIdx.x] = src[(size_t)(r0 + i) * C + c0 + threadIdx.x];
    __syncthreads();
    for (int i = threadIdx.y; i < 32; i += 8) {
        float v = t[threadIdx.x][i];
        if (OP == 2) v = softplus_f(v) * (1.0f / NH);
        dst[(size_t)(c0 + i) * R + r0 + threadIdx.x] = f2b(v);
    }
}

// bf16 -> bf16 transpose; grid (C/64, R/64), block (64,8)
__global__ __launch_bounds__(512) void transpose_bf16_kernel(
    u16* __restrict__ dst, const u16* __restrict__ src, int R, int C)
{
    __shared__ u16 t[64][65];
    const int c0 = blockIdx.x * 64, r0 = blockIdx.y * 64;
    for (int i = threadIdx.y; i < 64; i += 8)
        t[i][threadIdx.x] = src[(size_t)(r0 + i) * C + c0 + threadIdx.x];
    __syncthreads();
    for (int i = threadIdx.y; i < 64; i += 8)
        dst[(size_t)(c0 + i) * R + r0 + threadIdx.x] = t[threadIdx.x][i];
}

__global__ void ew_softplus_f32(float* __restrict__ dst, const float* __restrict__ src, long n) {
    long i = (long)blockIdx.x * blockDim.x + threadIdx.x;
    const long stride = (long)gridDim.x * blockDim.x;
    for (; i < n; i += stride) dst[i] = softplus_f(src[i]);
}

__global__ void ew_rehu_f32(float* __restrict__ dst, const float* __restrict__ src, long n) {
    long i = (long)blockIdx.x * blockDim.x + threadIdx.x;
    const long stride = (long)gridDim.x * blockDim.x;
    for (; i < n; i += stride) dst[i] = rehu_f(src[i], C_REHU_D);
}

__global__ void clear_kernel(float* __restrict__ dst, long n) {
    long i = (long)blockIdx.x * blockDim.x + threadIdx.x;
    const long stride = (long)gridDim.x * blockDim.x;
    for (; i < n; i += stride) dst[i] = 0.0f;
}

__global__ void fxinit_kernel(float* __restrict__ fxb, const float* __restrict__ fb2p) {
    long i = (long)blockIdx.x * blockDim.x + threadIdx.x;
    const long n = (long)NB * ND;
    const long stride = (long)gridDim.x * blockDim.x;
    for (; i < n; i += stride) fxb[i] = fb2p[i & (ND - 1)];
}

__global__ void fb2p_kernel(float* __restrict__ dst, const float* __restrict__ fb2) {
    const int c = threadIdx.x;
    dst[c] = (c < NOUT) ? fb2[c] : 1.0f;
}

// a2_0[j] = vb1[j] + (1/H) * sum_k z1_0[k] * softplus(vU0[j,k])
__global__ __launch_bounds__(256) void a20_kernel(
    float* __restrict__ a20, const float* __restrict__ z10,
    const float* __restrict__ vU0, const float* __restrict__ vb1)
{
    __shared__ float sbuf[4];
    const int j = blockIdx.x;
    float sum = 0.0f;
    const float* row = vU0 + (size_t)j * NH;
    for (int k = threadIdx.x; k < NH; k += 256) sum += z10[k] * softplus_f(row[k]);
    sum = block_reduce_sum(sum, sbuf);
    if (threadIdx.x == 0) a20[j] = vb1[j] + sum * (1.0f / NH);
}

// icnn0 = vb2 + sum_j rehu(a2_0[j]) * spU1[j]   (vU1.shape[0] == 1 -> no /H)
__global__ __launch_bounds__(256) void icnn0_kernel(
    float* __restrict__ ic0, const float* __restrict__ a20,
    const float* __restrict__ spU1, const float* __restrict__ vb2)
{
    __shared__ float sbuf[4];
    float sum = 0.0f;
    for (int j = threadIdx.x; j < NH; j += 256) sum += rehu_f(a20[j], C_REHU_D) * spU1[j];
    sum = block_reduce_sum(sum, sbuf);
    if (threadIdx.x == 0) ic0[0] = vb2[0] + sum;
}

// per row b: d1 = x.vW2, d2 = ||x||^2; diff = d1 + vb2 + zacc[b] - ic0
// sS = clamp(diff,0,1); sVx = rehu(diff,1) + eps*d2; ga2[b,:] = sS*spU1*drehu(a2)
__global__ __launch_bounds__(256) void rowfin_ga2_kernel(
    float* __restrict__ sS, float* __restrict__ sVx, u16* __restrict__ ga2,
    const float* __restrict__ x, const u16* __restrict__ a2b,
    const float* __restrict__ zacc, const float* __restrict__ spU1,
    const float* __restrict__ vW2, const float* __restrict__ vb2,
    const float* __restrict__ ic0)
{
    __shared__ float sbuf[4];
    __shared__ float ssh;
    const int b = blockIdx.x;
    const int t = threadIdx.x;
    const float xv = x[(size_t)b * ND + t];
    const float d1 = block_reduce_sum(xv * vW2[t], sbuf);
    const float d2 = block_reduce_sum(xv * xv, sbuf);
    if (t == 0) {
        const float diff = d1 + vb2[0] + zacc[b] - ic0[0];
        const float s = fminf(fmaxf(diff / C_PSD_D, 0.0f), 1.0f);
        sS[b]  = s;
        sVx[b] = rehu_f(diff, C_PSD_D) + C_EPS * d2;
        ssh = s;
    }
    __syncthreads();
    const float s = ssh;
    const bf16x8 av = *reinterpret_cast<const bf16x8*>(a2b + (size_t)b * NH + t * 8);
    bf16x8 ov;
    #pragma unroll
    for (int j = 0; j < 8; ++j) {
        const float a2v = b2f((u16)av[j]);
        const float g = s * spU1[t * 8 + j] * drehu_f(a2v, C_REHU_D);
        ov[j] = (short)f2b(g);
    }
    *reinterpret_cast<bf16x8*>(ga2 + (size_t)b * NH + t * 8) = ov;
}

// gV[b,c] = s[b]*vW2[c] + 2*eps*x[b,c]
__global__ void gvinit_kernel(float* __restrict__ gV, const float* __restrict__ sS,
                              const float* __restrict__ vW2, const float* __restrict__ x,
                              long n) {
    long i = (long)blockIdx.x * blockDim.x + threadIdx.x;
    const long stride = (long)gridDim.x * blockDim.x;
    for (; i < n; i += stride) {
        const int b = (int)(i >> 8);
        const int c = (int)(i & (ND - 1));
        gV[i] = sS[b] * vW2[c] + 2.0f * C_EPS * x[i];
    }
}

__global__ __launch_bounds__(256) void final_kernel(
    float* __restrict__ out, const float* __restrict__ gV,
    const float* __restrict__ fx, const float* __restrict__ sVx)
{
    __shared__ float sbuf[4];
    __shared__ float scoef;
    const int b = blockIdx.x;
    const int t = threadIdx.x;
    const float g = gV[(size_t)b * ND + t];
    const float f = fx[(size_t)b * ND + t];
    const float gf = block_reduce_sum(g * f, sbuf);
    const float gg = block_reduce_sum(g * g, sbuf);
    if (t == 0) {
        const float num = fmaxf(gf + C_ALPHA * sVx[b], 0.0f);
        scoef = num / gg;
    }
    __syncthreads();
    const float coef = scoef;
    if (t < NOUT) out[(size_t)b * NOUT + t] = f - g * coef;
}

extern "C" void kernel_launch(void* const* d_in, const int* in_sizes, int n_in,
                              void* d_out, int out_size, void* d_ws, size_t ws_size,
                              hipStream_t stream)
{
    const float* x   = (const float*)d_in[0];
    const float* fW0 = (const float*)d_in[1];
    const float* fb0 = (const float*)d_in[2];
    const float* fW1 = (const float*)d_in[3];
    const float* fb1 = (const float*)d_in[4];
    const float* fW2 = (const float*)d_in[5];
    const float* fb2 = (const float*)d_in[6];
    const float* vW0 = (const float*)d_in[7];
    const float* vb0 = (const float*)d_in[8];
    const float* vW1 = (const float*)d_in[9];
    const float* vb1 = (const float*)d_in[10];
    const float* vW2 = (const float*)d_in[11];
    const float* vb2 = (const float*)d_in[12];
    const float* vU0 = (const float*)d_in[13];
    const float* vU1 = (const float*)d_in[14];
    float* out = (float*)d_out;
    (void)in_sizes; (void)n_in; (void)out_size; (void)d_ws; (void)ws_size;

    u16 *xbf, *buf1, *buf2, *z1b, *a2b, *fW0b, *fW1b, *fW2b, *vW0b, *vW1b, *spU0b, *spU0Tb, *vW0Tb, *vW1Tb;
    float *fxb, *gVb, *fb2p, *spU1, *z10, *a20, *ic0, *zacc, *sS, *sVx;
    hipGetSymbolAddress((void**)&xbf,   HIP_SYMBOL(g_xbf));
    hipGetSymbolAddress((void**)&buf1,  HIP_SYMBOL(g_buf1));
    hipGetSymbolAddress((void**)&buf2,  HIP_SYMBOL(g_buf2));
    hipGetSymbolAddress((void**)&z1b,   HIP_SYMBOL(g_z1));
    hipGetSymbolAddress((void**)&a2b,   HIP_SYMBOL(g_a2b));
    hipGetSymbolAddress((void**)&fxb,   HIP_SYMBOL(g_fxb));
    hipGetSymbolAddress((void**)&gVb,   HIP_SYMBOL(g_gVb));
    hipGetSymbolAddress((void**)&fW0b,  HIP_SYMBOL(g_fW0b));
    hipGetSymbolAddress((void**)&fW1b,  HIP_SYMBOL(g_fW1b));
    hipGetSymbolAddress((void**)&fW2b,  HIP_SYMBOL(g_fW2b));
    hipGetSymbolAddress((void**)&vW0b,  HIP_SYMBOL(g_vW0b));
    hipGetSymbolAddress((void**)&vW1b,  HIP_SYMBOL(g_vW1b));
    hipGetSymbolAddress((void**)&spU0b, HIP_SYMBOL(g_spU0b));
    hipGetSymbolAddress((void**)&spU0Tb,HIP_SYMBOL(g_spU0Tb));
    hipGetSymbolAddress((void**)&vW0Tb, HIP_SYMBOL(g_vW0Tb));
    hipGetSymbolAddress((void**)&vW1Tb, HIP_SYMBOL(g_vW1Tb));
    hipGetSymbolAddress((void**)&fb2p,  HIP_SYMBOL(g_fb2p));
    hipGetSymbolAddress((void**)&spU1,  HIP_SYMBOL(g_spU1));
    hipGetSymbolAddress((void**)&z10,   HIP_SYMBOL(g_z10));
    hipGetSymbolAddress((void**)&a20,   HIP_SYMBOL(g_a20));
    hipGetSymbolAddress((void**)&ic0,   HIP_SYMBOL(g_ic0));
    hipGetSymbolAddress((void**)&zacc,  HIP_SYMBOL(g_zacc));
    hipGetSymbolAddress((void**)&sS,    HIP_SYMBOL(g_sS));
    hipGetSymbolAddress((void**)&sVx,   HIP_SYMBOL(g_sVx));

    // ---- one-time precomputes ----
    cast_kernel<0><<<1024, 256, 0, stream>>>(xbf, x, (long)NB * ND);
    cast_kernel<0><<<512, 256, 0, stream>>>(fW0b, fW0, (long)NH * ND);
    cast_kernel<0><<<2048, 256, 0, stream>>>(fW1b, fW1, (long)NH * NH);
    castpad_kernel<<<512, 256, 0, stream>>>(fW2b, fW2, (long)NOUT * NH, (long)ND * NH);
    cast_kernel<0><<<512, 256, 0, stream>>>(vW0b, vW0, (long)NH * ND);
    cast_kernel<0><<<512, 256, 0, stream>>>(vW1b, vW1, (long)NH * ND);
    cast_kernel<2><<<2048, 256, 0, stream>>>(spU0b, vU0, (long)NH * NH);
    transpose_bf16_kernel<<<dim3(32, 32), dim3(64, 8), 0, stream>>>(spU0Tb, spU0b, NH, NH);
    transpose_cast_kernel<0><<<dim3(8, 64), dim3(32, 8), 0, stream>>>(vW0Tb, vW0, NH, ND);
    transpose_cast_kernel<0><<<dim3(8, 64), dim3(32, 8), 0, stream>>>(vW1Tb, vW1, NH, ND);
    ew_softplus_f32<<<8, 256, 0, stream>>>(spU1, vU1, NH);
    ew_rehu_f32<<<8, 256, 0, stream>>>(z10, vb0, NH);
    fb2p_kernel<<<1, 256, 0, stream>>>(fb2p, fb2);
    a20_kernel<<<NH, 256, 0, stream>>>(a20, z10, vU0, vb1);
    icnn0_kernel<<<1, 256, 0, stream>>>(ic0, a20, spU1, vb2);
    clear_kernel<<<64, 256, 0, stream>>>(zacc, NB);

    // ---- fhat MLP ----
    gemm8<0><<<512, 512, 0, stream>>>(buf1, xbf, ND, fW0b, ND, 4,
        nullptr, 0, nullptr, 0, fb0, nullptr, nullptr, nullptr, NH, 4);
    gemm8<0><<<512, 512, 0, stream>>>(buf2, buf1, NH, fW1b, NH, 32,
        nullptr, 0, nullptr, 0, fb1, nullptr, nullptr, nullptr, NH, 32);
    fxinit_kernel<<<2048, 256, 0, stream>>>(fxb, fb2p);
    mfma_gemm<0><<<dim3(256, 2), 256, 0, stream>>>(fxb, buf2, fW2b, NH, NH,
        nullptr, nullptr, NB, ND, NH / 2);

    // ---- ICNN forward ----
    gemm8<2><<<512, 512, 0, stream>>>(z1b, xbf, ND, vW0b, ND, 4,
        nullptr, 0, nullptr, 0, vb0, nullptr, nullptr, nullptr, NH, 4);
    // a2 = x@vW1^T + vb1 + z1@(spU0/H)^T  (two K-segments) + per-row zacc
    gemm8<3><<<512, 512, 0, stream>>>(a2b, xbf, ND, vW1b, ND, 4,
        z1b, NH, spU0b, NH, vb1, nullptr, zacc, spU1, NH, 36);
    rowfin_ga2_kernel<<<NB, 256, 0, stream>>>(sS, sVx, buf1, x, a2b, zacc, spU1, vW2, vb2, ic0);

    // ---- backward ----
    // g_a1 = (g_a2 @ (spU0/H)) * drehu(a1)  with drehu recovered from z1 bf16
    gemm8<4><<<512, 512, 0, stream>>>(buf2, buf1, NH, spU0Tb, NH, 32,
        nullptr, 0, nullptr, 0, nullptr, z1b, nullptr, nullptr, NH, 32);
    gvinit_kernel<<<2048, 256, 0, stream>>>(gVb, sS, vW2, x, (long)NB * ND);
    // gV += g_a2@vW1T (seg 0) + g_a1@vW0T (seg 1), one launch
    mfma_gemm<1><<<dim3(256, 2), 256, 0, stream>>>(gVb, buf1, vW1Tb, NH, NH,
        buf2, vW0Tb, NB, ND, NH);

    final_kernel<<<NB, 256, 0, stream>>>(out, gVb, fxb, sVx);
}